// Round 3
// baseline (238.763 us; speedup 1.0000x reference)
//
#include <hip/hip_runtime.h>

// Problem constants (reference: H = W = 2048, C = 8, N = 1e6)
#define HH 2048
#define WW 2048
#define CC 8
#define MODV 2044.0f   // H - 4

typedef float v4f __attribute__((ext_vector_type(4)));

struct PtInfo {
    const float* p00;   // &visible[i0][i1][0]
    float d0, d1, m;
};

__device__ __forceinline__ PtInfo mkpt(float x, float y, const float* __restrict__ visible) {
    // c = (coord - 1) mod 2044 + 1   (floored mod, positive divisor)
    float cx = fmodf(x - 1.0f, MODV); if (cx < 0.0f) cx += MODV; cx += 1.0f;
    float cy = fmodf(y - 1.0f, MODV); if (cy < 0.0f) cy += MODV; cy += 1.0f;
    float fx = floorf(cx);
    float fy = floorf(cy);
    PtInfo r;
    r.d0 = cx - fx;                      // row fraction
    r.d1 = cy - fy;                      // col fraction
    r.m  = (cx > (float)HH) ? 0.0f : 1.0f;  // reference's (unreachable) zeroing
    int i0 = (int)fx;                    // row in [1,2044]
    int i1 = (int)fy;                    // col in [1,2044]
    r.p00 = visible + ((size_t)i0 * WW + (size_t)i1) * CC;
    return r;
}

__device__ __forceinline__ float lerp3(float tl, float tr, float bl, float br,
                                       float d0, float d1) {
    float mb = br + d0 * (bl - br);
    float mt = tr + d0 * (tl - tr);
    return mb + d1 * (mt - mb);
}

__device__ __forceinline__ void compute_store(
    v4f tl0, v4f tl1, v4f bl0, v4f bl1,
    v4f tr0, v4f tr1, v4f br0, v4f br1,
    float d0, float d1, float m, float* po)
{
    v4f o0, o1;
    o0.x = m * lerp3(tl0.x, tr0.x, bl0.x, br0.x, d0, d1);
    o0.y = m * lerp3(tl0.y, tr0.y, bl0.y, br0.y, d0, d1);
    o0.z = m * lerp3(tl0.z, tr0.z, bl0.z, br0.z, d0, d1);
    o0.w = m * lerp3(tl0.w, tr0.w, bl0.w, br0.w, d0, d1);
    o1.x = m * lerp3(tl1.x, tr1.x, bl1.x, br1.x, d0, d1);
    o1.y = m * lerp3(tl1.y, tr1.y, bl1.y, br1.y, d0, d1);
    o1.z = m * lerp3(tl1.z, tr1.z, bl1.z, br1.z, d0, d1);
    o1.w = m * lerp3(tl1.w, tr1.w, bl1.w, br1.w, d0, d1);
    __builtin_nontemporal_store(o0, reinterpret_cast<v4f*>(po));
    __builtin_nontemporal_store(o1, reinterpret_cast<v4f*>(po + 4));
}

#define LD4(p) (*reinterpret_cast<const v4f*>(p))

// Two points per thread: 16 gather loads in flight per lane before first use.
__global__ __launch_bounds__(256) void idx2pixel_kernel(
    const float* __restrict__ coords,   // (N, 2)
    const float* __restrict__ visible,  // (H, W, C) row-major
    float* __restrict__ out,            // (N, C)
    int n)
{
    int t = blockIdx.x * blockDim.x + threadIdx.x;
    int pa = 2 * t;
    int pb = 2 * t + 1;
    if (pa >= n) return;

    // coords for both points in one coalesced 16B nontemporal load
    v4f c4 = __builtin_nontemporal_load(
        reinterpret_cast<const v4f*>(coords) + t);

    PtInfo A = mkpt(c4.x, c4.y, visible);
    bool hasB = pb < n;
    // For a missing B, alias A's addresses (loads stay in-bounds, result discarded)
    PtInfo B = hasB ? mkpt(c4.z, c4.w, visible) : A;

    const float* a00 = A.p00;
    const float* a10 = A.p00 + (size_t)WW * CC;
    const float* b00 = B.p00;
    const float* b10 = B.p00 + (size_t)WW * CC;

    // Issue all 16 loads back-to-back (straight-line, no intervening use)
    v4f Atl0 = LD4(a00);      v4f Atl1 = LD4(a00 + 4);
    v4f Abl0 = LD4(a00 + 8);  v4f Abl1 = LD4(a00 + 12);
    v4f Atr0 = LD4(a10);      v4f Atr1 = LD4(a10 + 4);
    v4f Abr0 = LD4(a10 + 8);  v4f Abr1 = LD4(a10 + 12);
    v4f Btl0 = LD4(b00);      v4f Btl1 = LD4(b00 + 4);
    v4f Bbl0 = LD4(b00 + 8);  v4f Bbl1 = LD4(b00 + 12);
    v4f Btr0 = LD4(b10);      v4f Btr1 = LD4(b10 + 4);
    v4f Bbr0 = LD4(b10 + 8);  v4f Bbr1 = LD4(b10 + 12);

    compute_store(Atl0, Atl1, Abl0, Abl1, Atr0, Atr1, Abr0, Abr1,
                  A.d0, A.d1, A.m, out + (size_t)pa * CC);
    if (hasB) {
        compute_store(Btl0, Btl1, Bbl0, Bbl1, Btr0, Btr1, Bbr0, Bbr1,
                      B.d0, B.d1, B.m, out + (size_t)pb * CC);
    }
}

extern "C" void kernel_launch(void* const* d_in, const int* in_sizes, int n_in,
                              void* d_out, int out_size, void* d_ws, size_t ws_size,
                              hipStream_t stream) {
    const float* coords  = (const float*)d_in[0];  // (N, 2) fp32
    const float* visible = (const float*)d_in[1];  // (2048, 2048, 8) fp32
    float* out = (float*)d_out;                    // (N, 8) fp32
    int n = in_sizes[0] / 2;

    int npair = (n + 1) / 2;
    int block = 256;
    int grid = (npair + block - 1) / block;
    idx2pixel_kernel<<<grid, block, 0, stream>>>(coords, visible, out, n);
}